// Round 1
// 1275.532 us; speedup vs baseline: 1.0564x; 1.0564x over previous
//
#include <hip/hip_runtime.h>

typedef unsigned short u16;
typedef unsigned int u32;
typedef __attribute__((ext_vector_type(8))) short short8;   // 8 x bf16 bits (4 VGPRs)
typedef __attribute__((ext_vector_type(8))) u16 ushort8;
typedef __attribute__((ext_vector_type(4))) float f32x4;

#define IN_DIM 4096
#define OUT_DIM 11008
#define MDIM 8192

// round-to-nearest-even fp32 -> bf16 bits
__device__ __forceinline__ u16 f2bf(float f) {
  union { float f; u32 u; } v; v.f = f;
  const u32 u = v.u;
  return (u16)((u + 0x7FFFu + ((u >> 16) & 1u)) >> 16);
}

// ---------------------------------------------------------------------------
// Kernel 1: AWQ dequant. 4 int32 -> 8 weights -> one 16B bf16 store per thread.
// ---------------------------------------------------------------------------
__global__ void dequant_kernel(const int* __restrict__ packed,
                               const float* __restrict__ scales,
                               const float* __restrict__ offsets,
                               const float* __restrict__ inv_scale,
                               u16* __restrict__ W) {
  const int t = blockIdx.x * 256 + threadIdx.x;
  const int4 p = ((const int4*)packed)[t];
  const int f0 = t * 8;
  const int g = f0 >> 7;
  const int i0 = f0 & (IN_DIM - 1);
  const float s = scales[g];
  const float o = offsets[g];
  const float4 iv0 = *(const float4*)(inv_scale + i0);
  const float4 iv1 = *(const float4*)(inv_scale + i0 + 4);

  const float w0 = fmaf((float)(p.x & 15),        s, o) * iv0.x;
  const float w1 = fmaf((float)((p.x >> 4) & 15), s, o) * iv0.y;
  const float w2 = fmaf((float)(p.y & 15),        s, o) * iv0.z;
  const float w3 = fmaf((float)((p.y >> 4) & 15), s, o) * iv0.w;
  const float w4 = fmaf((float)(p.z & 15),        s, o) * iv1.x;
  const float w5 = fmaf((float)((p.z >> 4) & 15), s, o) * iv1.y;
  const float w6 = fmaf((float)(p.w & 15),        s, o) * iv1.z;
  const float w7 = fmaf((float)((p.w >> 4) & 15), s, o) * iv1.w;

  ushort8 r;
  r[0] = f2bf(w0); r[1] = f2bf(w1); r[2] = f2bf(w2); r[3] = f2bf(w3);
  r[4] = f2bf(w4); r[5] = f2bf(w5); r[6] = f2bf(w6); r[7] = f2bf(w7);
  *(ushort8*)(W + f0) = r;
}

// ---------------------------------------------------------------------------
// Kernel 2: x fp32 -> bf16.
// ---------------------------------------------------------------------------
__global__ void castx_kernel(const float* __restrict__ x, u16* __restrict__ xb) {
  const int t = blockIdx.x * 256 + threadIdx.x;
  const float4 a = ((const float4*)x)[t * 2];
  const float4 b = ((const float4*)x)[t * 2 + 1];
  ushort8 r;
  r[0] = f2bf(a.x); r[1] = f2bf(a.y); r[2] = f2bf(a.z); r[3] = f2bf(a.w);
  r[4] = f2bf(b.x); r[5] = f2bf(b.y); r[6] = f2bf(b.z); r[7] = f2bf(b.w);
  *(ushort8*)(xb + t * 8) = r;
}

// ---------------------------------------------------------------------------
// Kernel 3: bf16 GEMM, C = A * B^T + bias.
// 256x256 tile, 8 waves (2M x 4N), K-step = 32.
// LDS = 4-deep K-step pipeline: lds[4][A|B][256*32] = 128 KiB.
// Stage for step t+3 issued during step t; s_waitcnt vmcnt(8) once per step
// keeps 2 steps (8 loads/thread) in flight across the barriers (T3+T4).
// Swizzle: chunk ^= (row>>1)&3  (bank-exact for ds_read_b128 on [256][32]),
// applied on the pre-swizzled global source (linear global_load_lds dest)
// and identically on fragment reads.
// ---------------------------------------------------------------------------
__device__ __forceinline__ void gload_lds16(const u16* g, u16* l) {
  using gvp = const __attribute__((address_space(1))) void*;
  using lvp = __attribute__((address_space(3))) void*;
  __builtin_amdgcn_global_load_lds((gvp)g, (lvp)l, 16, 0, 0);
}

#define NB_N 43            // 11008 / 256
#define NB_M 32            // 8192 / 256
#define GROUP_N 8          // n-blocks per supertile == #XCDs
#define NTK 128            // 4096 / 32 K-steps

__launch_bounds__(512, 2)
__global__ void gemm_kernel(const u16* __restrict__ A,   // [MDIM, IN_DIM] bf16
                            const u16* __restrict__ B,   // [OUT_DIM, IN_DIM] bf16
                            const float* __restrict__ bias,
                            float* __restrict__ C) {
  constexpr int K = IN_DIM;
  constexpr int N = OUT_DIM;
  __shared__ u16 lds[4][2][8192];   // [buf][A=0,B=1][256 rows * 32 cols] = 128 KiB

  const int tid  = threadIdx.x;
  const int wave = tid >> 6;
  const int lane = tid & 63;
  const int lc   = lane & 15;
  const int lr   = lane >> 4;

  // --- block -> tile mapping: supertiles of all-m x GROUP_N n, n fastest ----
  const int bid   = blockIdx.x;
  const int group = bid >> 8;            // / (NB_M * GROUP_N) = /256
  const int rem   = bid & 255;
  const int gn    = group * GROUP_N;
  const int gwid  = (NB_N - gn) < GROUP_N ? (NB_N - gn) : GROUP_N;
  const int nb    = gn + rem % gwid;
  const int mb    = rem / gwid;
  const int m0 = mb * 256;
  const int n0 = nb * 256;

  // --- staging addressing ---------------------------------------------------
  // thread t, load j: LDS elem off = j*4096 + t*8  -> row = j*128 + (t>>2),
  // stored chunk = t&3; source chunk = (t&3) ^ ((row>>1)&3) = (t&3)^((t>>3)&3)
  const int srow   = tid >> 2;                       // 0..127
  const int schunk = (tid & 3) ^ ((tid >> 3) & 3);
  const u16* gA = A + (size_t)(m0 + srow) * K + schunk * 8;
  const u16* gB = B + (size_t)(n0 + srow) * K + schunk * 8;

#define STAGE_A(bufi, kc) do {                                        \
    const u16* _g = gA + (kc);                                        \
    gload_lds16(_g,                   &lds[bufi][0][0]    + tid * 8); \
    gload_lds16(_g + (size_t)128 * K, &lds[bufi][0][4096] + tid * 8); \
  } while (0)
#define STAGE_B(bufi, kc) do {                                        \
    const u16* _g = gB + (kc);                                        \
    gload_lds16(_g,                   &lds[bufi][1][0]    + tid * 8); \
    gload_lds16(_g + (size_t)128 * K, &lds[bufi][1][4096] + tid * 8); \
  } while (0)

  // --- fragment addressing (read through the same swizzle) -----------------
  // A row = wr*128 + (mi)*16 + lc ; B row = wc*64 + ni*16 + lc ; chunk = lr.
  // (row>>1)&3 == (lc>>1)&3 for all row-bases that are multiples of 16.
  const int wr = wave >> 2;    // 0..1
  const int wc = wave & 3;     // 0..3
  const int cswz = (lr ^ ((lc >> 1) & 3)) * 8;     // swizzled 16B chunk, elems
  const u16* faBase = &lds[0][0][0] + (wr * 128 + lc) * 32 + cswz;
  const u16* fbBase = &lds[0][1][0] + (wc * 64  + lc) * 32 + cswz;

  f32x4 acc[8][4] = {};

  // --- prologue: stage K-steps 0,1,2 into bufs 0,1,2 (12 loads/thread) -----
  STAGE_A(0, 0);  STAGE_B(0, 0);
  STAGE_A(1, 32); STAGE_B(1, 32);
  STAGE_A(2, 64); STAGE_B(2, 64);
  asm volatile("s_waitcnt vmcnt(8)" ::: "memory");   // step 0 landed
  __builtin_amdgcn_s_barrier();

  for (int t = 0; t < NTK; ++t) {
    const int b = t & 3;
    const u16* fa = faBase + b * 16384;
    const u16* fb = fbBase + b * 16384;
    const int ts   = t + 3;
    const int kcol = (ts < NTK ? ts : NTK - 1) * 32;  // tail: benign re-stage
    const int tb   = ts & 3;                          // == (t-1)&3, just freed

    // ---- phase 0: C-half 0 (mi 0..3) ----
    STAGE_A(tb, kcol);
    short8 bf[4], af[4];
#pragma unroll
    for (int i = 0; i < 4; ++i) bf[i] = *(const short8*)(fb + i * 512);
#pragma unroll
    for (int i = 0; i < 4; ++i) af[i] = *(const short8*)(fa + i * 512);
    __builtin_amdgcn_s_setprio(1);
#pragma unroll
    for (int mi = 0; mi < 4; ++mi)
#pragma unroll
      for (int ni = 0; ni < 4; ++ni)
        acc[mi][ni] = __builtin_amdgcn_mfma_f32_16x16x32_bf16(
            af[mi], bf[ni], acc[mi][ni], 0, 0, 0);
    __builtin_amdgcn_s_setprio(0);
    __builtin_amdgcn_s_barrier();

    // ---- phase 1: C-half 1 (mi 4..7), B frags reused ----
    STAGE_B(tb, kcol);
#pragma unroll
    for (int i = 0; i < 4; ++i) af[i] = *(const short8*)(fa + 2048 + i * 512);
    __builtin_amdgcn_s_setprio(1);
#pragma unroll
    for (int mi = 0; mi < 4; ++mi)
#pragma unroll
      for (int ni = 0; ni < 4; ++ni)
        acc[4 + mi][ni] = __builtin_amdgcn_mfma_f32_16x16x32_bf16(
            af[mi], bf[ni], acc[4 + mi][ni], 0, 0, 0);
    __builtin_amdgcn_s_setprio(0);
    // counted wait: leaves steps t+1, t+2 (8 loads/thread) in flight
    asm volatile("s_waitcnt vmcnt(8)" ::: "memory");
    __builtin_amdgcn_s_barrier();
  }

  // drain tail dummy stages before LDS could be deallocated
  asm volatile("s_waitcnt vmcnt(0)" ::: "memory");

  // --- epilogue: C/D layout col = lane&15, row = (lane>>4)*4 + reg ---------
  const int cm = m0 + wr * 128 + lr * 4;
  const int cn = n0 + wc * 64 + lc;
#pragma unroll
  for (int ni = 0; ni < 4; ++ni) {
    const int n = cn + ni * 16;
    const float bv = bias[n];
#pragma unroll
    for (int mi = 0; mi < 8; ++mi) {
      const int m = cm + mi * 16;
      float* cp = C + (size_t)m * N + n;
      cp[0]             = acc[mi][ni][0] + bv;
      cp[(size_t)N]     = acc[mi][ni][1] + bv;
      cp[(size_t)2 * N] = acc[mi][ni][2] + bv;
      cp[(size_t)3 * N] = acc[mi][ni][3] + bv;
    }
  }
}

// ---------------------------------------------------------------------------
extern "C" void kernel_launch(void* const* d_in, const int* in_sizes, int n_in,
                              void* d_out, int out_size, void* d_ws, size_t ws_size,
                              hipStream_t stream) {
  const float* x         = (const float*)d_in[0];
  const int*   packed    = (const int*)d_in[1];
  const float* scales    = (const float*)d_in[2];
  const float* offsets   = (const float*)d_in[3];
  const float* inv_scale = (const float*)d_in[4];
  const float* bias      = (const float*)d_in[5];
  float* out = (float*)d_out;

  u16* W  = (u16*)d_ws;                          // bf16 [OUT, IN]
  u16* xb = W + (size_t)OUT_DIM * IN_DIM;        // bf16 [M, IN]

  dequant_kernel<<<dim3((OUT_DIM * IN_DIM / 8) / 256), dim3(256), 0, stream>>>(
      packed, scales, offsets, inv_scale, W);
  castx_kernel<<<dim3((MDIM * IN_DIM / 8) / 256), dim3(256), 0, stream>>>(x, xb);
  gemm_kernel<<<dim3(NB_N * NB_M), dim3(512), 0, stream>>>(xb, W, bias, out);
}

// Round 2
// 1274.161 us; speedup vs baseline: 1.0575x; 1.0011x over previous
//
#include <hip/hip_runtime.h>

typedef unsigned short u16;
typedef unsigned int u32;
typedef __attribute__((ext_vector_type(8))) short short8;   // 8 x bf16 bits (4 VGPRs)
typedef __attribute__((ext_vector_type(8))) u16 ushort8;
typedef __attribute__((ext_vector_type(4))) float f32x4;

#define IN_DIM 4096
#define OUT_DIM 11008
#define MDIM 8192

// round-to-nearest-even fp32 -> bf16 bits
__device__ __forceinline__ u16 f2bf(float f) {
  union { float f; u32 u; } v; v.f = f;
  const u32 u = v.u;
  return (u16)((u + 0x7FFFu + ((u >> 16) & 1u)) >> 16);
}

// ---------------------------------------------------------------------------
// Kernel 1: AWQ dequant. 4 int32 -> 8 weights -> one 16B bf16 store per thread.
// ---------------------------------------------------------------------------
__global__ void dequant_kernel(const int* __restrict__ packed,
                               const float* __restrict__ scales,
                               const float* __restrict__ offsets,
                               const float* __restrict__ inv_scale,
                               u16* __restrict__ W) {
  const int t = blockIdx.x * 256 + threadIdx.x;
  const int4 p = ((const int4*)packed)[t];
  const int f0 = t * 8;
  const int g = f0 >> 7;
  const int i0 = f0 & (IN_DIM - 1);
  const float s = scales[g];
  const float o = offsets[g];
  const float4 iv0 = *(const float4*)(inv_scale + i0);
  const float4 iv1 = *(const float4*)(inv_scale + i0 + 4);

  const float w0 = fmaf((float)(p.x & 15),        s, o) * iv0.x;
  const float w1 = fmaf((float)((p.x >> 4) & 15), s, o) * iv0.y;
  const float w2 = fmaf((float)(p.y & 15),        s, o) * iv0.z;
  const float w3 = fmaf((float)((p.y >> 4) & 15), s, o) * iv0.w;
  const float w4 = fmaf((float)(p.z & 15),        s, o) * iv1.x;
  const float w5 = fmaf((float)((p.z >> 4) & 15), s, o) * iv1.y;
  const float w6 = fmaf((float)(p.w & 15),        s, o) * iv1.z;
  const float w7 = fmaf((float)((p.w >> 4) & 15), s, o) * iv1.w;

  ushort8 r;
  r[0] = f2bf(w0); r[1] = f2bf(w1); r[2] = f2bf(w2); r[3] = f2bf(w3);
  r[4] = f2bf(w4); r[5] = f2bf(w5); r[6] = f2bf(w6); r[7] = f2bf(w7);
  *(ushort8*)(W + f0) = r;
}

// ---------------------------------------------------------------------------
// Kernel 2: x fp32 -> bf16.
// ---------------------------------------------------------------------------
__global__ void castx_kernel(const float* __restrict__ x, u16* __restrict__ xb) {
  const int t = blockIdx.x * 256 + threadIdx.x;
  const float4 a = ((const float4*)x)[t * 2];
  const float4 b = ((const float4*)x)[t * 2 + 1];
  ushort8 r;
  r[0] = f2bf(a.x); r[1] = f2bf(a.y); r[2] = f2bf(a.z); r[3] = f2bf(a.w);
  r[4] = f2bf(b.x); r[5] = f2bf(b.y); r[6] = f2bf(b.z); r[7] = f2bf(b.w);
  *(ushort8*)(xb + t * 8) = r;
}

// ---------------------------------------------------------------------------
// Kernel 3: bf16 GEMM, C = A * B^T + bias.
// 256x256 tile, 8 waves (2M x 4N), K-step = 32.
// LDS = 4-deep K-step pipeline: lds[4][A|B][256*32] = 128 KiB.
// Two-window phases (m201 shape):
//   {ds_read frags + stage issue} -> s_barrier -> {lgkm drain + 16 MFMA} -> s_barrier
// so LDS-read latency is absorbed during the barrier crossing and the compute
// window is pure MFMA. Counted s_waitcnt vmcnt(8) once per K-step (never 0 in
// the main loop): stages for steps t+1..t+3 stay in flight across barriers.
// Swizzle: chunk ^= (row>>1)&3 (bank-exact for ds_read_b128 on [256][32]),
// applied on the pre-swizzled global source (linear global_load_lds dest)
// and identically on fragment reads.
// ---------------------------------------------------------------------------
__device__ __forceinline__ void gload_lds16(const u16* g, u16* l) {
  using gvp = const __attribute__((address_space(1))) void*;
  using lvp = __attribute__((address_space(3))) void*;
  __builtin_amdgcn_global_load_lds((gvp)g, (lvp)l, 16, 0, 0);
}

#define NB_N 43            // 11008 / 256
#define NB_M 32            // 8192 / 256
#define GROUP_N 8          // n-blocks per supertile == #XCDs
#define NTK 128            // 4096 / 32 K-steps

__launch_bounds__(512, 2)
__global__ void gemm_kernel(const u16* __restrict__ A,   // [MDIM, IN_DIM] bf16
                            const u16* __restrict__ B,   // [OUT_DIM, IN_DIM] bf16
                            const float* __restrict__ bias,
                            float* __restrict__ C) {
  constexpr int K = IN_DIM;
  constexpr int N = OUT_DIM;
  __shared__ u16 lds[4][2][8192];   // [buf][A=0,B=1][256 rows * 32 cols] = 128 KiB

  const int tid  = threadIdx.x;
  const int wave = tid >> 6;
  const int lane = tid & 63;
  const int lc   = lane & 15;
  const int lr   = lane >> 4;

  // --- block -> tile mapping: supertiles of all-m x GROUP_N n, n fastest ----
  const int bid   = blockIdx.x;
  const int group = bid >> 8;            // / (NB_M * GROUP_N) = /256
  const int rem   = bid & 255;
  const int gn    = group * GROUP_N;
  const int gwid  = (NB_N - gn) < GROUP_N ? (NB_N - gn) : GROUP_N;
  const int nb    = gn + rem % gwid;
  const int mb    = rem / gwid;
  const int m0 = mb * 256;
  const int n0 = nb * 256;

  // --- staging addressing ---------------------------------------------------
  // thread t, load j: LDS elem off = j*4096 + t*8  -> row = j*128 + (t>>2),
  // stored chunk = t&3; source chunk = (t&3) ^ ((row>>1)&3) = (t&3)^((t>>3)&3)
  const int srow   = tid >> 2;                       // 0..127
  const int schunk = (tid & 3) ^ ((tid >> 3) & 3);
  const u16* gA = A + (size_t)(m0 + srow) * K + schunk * 8;
  const u16* gB = B + (size_t)(n0 + srow) * K + schunk * 8;

#define STAGE_A(bufi, kc) do {                                        \
    const u16* _g = gA + (kc);                                        \
    gload_lds16(_g,                   &lds[bufi][0][0]    + tid * 8); \
    gload_lds16(_g + (size_t)128 * K, &lds[bufi][0][4096] + tid * 8); \
  } while (0)
#define STAGE_B(bufi, kc) do {                                        \
    const u16* _g = gB + (kc);                                        \
    gload_lds16(_g,                   &lds[bufi][1][0]    + tid * 8); \
    gload_lds16(_g + (size_t)128 * K, &lds[bufi][1][4096] + tid * 8); \
  } while (0)

  // --- fragment addressing (read through the same swizzle) -----------------
  // A row = wr*128 + (mi)*16 + lc ; B row = wc*64 + ni*16 + lc ; chunk = lr.
  // (row>>1)&3 == (lc>>1)&3 for all row-bases that are multiples of 16.
  const int wr = wave >> 2;    // 0..1
  const int wc = wave & 3;     // 0..3
  const int cswz = (lr ^ ((lc >> 1) & 3)) * 8;     // swizzled 16B chunk, elems
  const u16* faBase = &lds[0][0][0] + (wr * 128 + lc) * 32 + cswz;
  const u16* fbBase = &lds[0][1][0] + (wc * 64  + lc) * 32 + cswz;

  f32x4 acc[8][4] = {};

  // --- prologue: stage K-steps 0,1,2 into bufs 0,1,2 (12 loads/thread) -----
  STAGE_A(0, 0);  STAGE_B(0, 0);
  STAGE_A(1, 32); STAGE_B(1, 32);
  STAGE_A(2, 64); STAGE_B(2, 64);
  asm volatile("s_waitcnt vmcnt(8)" ::: "memory");   // step 0 landed
  __builtin_amdgcn_s_barrier();

  for (int t = 0; t < NTK; ++t) {
    const int b = t & 3;
    const u16* fa = faBase + b * 16384;
    const u16* fb = fbBase + b * 16384;
    const int ts   = t + 3;
    const int kcol = (ts < NTK ? ts : NTK - 1) * 32;  // tail: benign re-stage
    const int tb   = ts & 3;                          // == (t-1)&3, just freed

    // ======== phase 0 ========
    // issue window: frag reads (buf b) + A-stage (buf tb), then barrier
    short8 bf[4], af[4];
#pragma unroll
    for (int i = 0; i < 4; ++i) bf[i] = *(const short8*)(fb + i * 512);
#pragma unroll
    for (int i = 0; i < 4; ++i) af[i] = *(const short8*)(fa + i * 512);
    STAGE_A(tb, kcol);
    __builtin_amdgcn_s_barrier();
    // compute window: pure MFMA (compiler-inserted lgkmcnt drain precedes)
    __builtin_amdgcn_s_setprio(1);
#pragma unroll
    for (int mi = 0; mi < 4; ++mi)
#pragma unroll
      for (int ni = 0; ni < 4; ++ni)
        acc[mi][ni] = __builtin_amdgcn_mfma_f32_16x16x32_bf16(
            af[mi], bf[ni], acc[mi][ni], 0, 0, 0);
    __builtin_amdgcn_s_setprio(0);
    __builtin_amdgcn_s_barrier();

    // ======== phase 1 ========
    // issue window: A-hi frag reads (buf b) + B-stage (buf tb), then barrier
#pragma unroll
    for (int i = 0; i < 4; ++i) af[i] = *(const short8*)(fa + 2048 + i * 512);
    STAGE_B(tb, kcol);
    __builtin_amdgcn_s_barrier();
    // compute window: pure MFMA (B frags reused from phase 0)
    __builtin_amdgcn_s_setprio(1);
#pragma unroll
    for (int mi = 0; mi < 4; ++mi)
#pragma unroll
      for (int ni = 0; ni < 4; ++ni)
        acc[4 + mi][ni] = __builtin_amdgcn_mfma_f32_16x16x32_bf16(
            af[mi], bf[ni], acc[4 + mi][ni], 0, 0, 0);
    __builtin_amdgcn_s_setprio(0);
    // counted wait: leaves steps t+2, t+3 (8 loads/thread) in flight;
    // following barrier makes "step t+1 landed" true workgroup-wide.
    asm volatile("s_waitcnt vmcnt(8)" ::: "memory");
    __builtin_amdgcn_s_barrier();
  }

  // drain tail dummy stages before LDS could be deallocated
  asm volatile("s_waitcnt vmcnt(0)" ::: "memory");

  // --- epilogue: C/D layout col = lane&15, row = (lane>>4)*4 + reg ---------
  const int cm = m0 + wr * 128 + lr * 4;
  const int cn = n0 + wc * 64 + lc;
#pragma unroll
  for (int ni = 0; ni < 4; ++ni) {
    const int n = cn + ni * 16;
    const float bv = bias[n];
#pragma unroll
    for (int mi = 0; mi < 8; ++mi) {
      const int m = cm + mi * 16;
      float* cp = C + (size_t)m * N + n;
      cp[0]             = acc[mi][ni][0] + bv;
      cp[(size_t)N]     = acc[mi][ni][1] + bv;
      cp[(size_t)2 * N] = acc[mi][ni][2] + bv;
      cp[(size_t)3 * N] = acc[mi][ni][3] + bv;
    }
  }
}

// ---------------------------------------------------------------------------
extern "C" void kernel_launch(void* const* d_in, const int* in_sizes, int n_in,
                              void* d_out, int out_size, void* d_ws, size_t ws_size,
                              hipStream_t stream) {
  const float* x         = (const float*)d_in[0];
  const int*   packed    = (const int*)d_in[1];
  const float* scales    = (const float*)d_in[2];
  const float* offsets   = (const float*)d_in[3];
  const float* inv_scale = (const float*)d_in[4];
  const float* bias      = (const float*)d_in[5];
  float* out = (float*)d_out;

  u16* W  = (u16*)d_ws;                          // bf16 [OUT, IN]
  u16* xb = W + (size_t)OUT_DIM * IN_DIM;        // bf16 [M, IN]

  dequant_kernel<<<dim3((OUT_DIM * IN_DIM / 8) / 256), dim3(256), 0, stream>>>(
      packed, scales, offsets, inv_scale, W);
  castx_kernel<<<dim3((MDIM * IN_DIM / 8) / 256), dim3(256), 0, stream>>>(x, xb);
  gemm_kernel<<<dim3(NB_N * NB_M), dim3(512), 0, stream>>>(xb, W, bias, out);
}